// Round 1
// 5437.352 us; speedup vs baseline: 1.0449x; 1.0449x over previous
//
#include <hip/hip_runtime.h>
#include <hip/hip_bf16.h>

typedef __hip_bfloat16 bf16;

__device__ __forceinline__ float b2f(bf16 v) { return __bfloat162float(v); }
__device__ __forceinline__ bf16 f2b(float v) { return __float2bfloat16(v); }

__device__ __forceinline__ void atomicAddF(float* p, float v) {
    unsafeAtomicAdd(p, v);   // hardware global_atomic_add_f32 on gfx950
}

// out[i,j] = sum_k x[i,k]*W[k,j] + b[j]   (x,W,b f32 -> out bf16), no relu
template<int F>
__global__ void proj_kernel(const float* __restrict__ x, const float* __restrict__ W,
                            const float* __restrict__ b, bf16* __restrict__ out, int n) {
    __shared__ float sW[F][64];
    __shared__ float sb[64];
    __shared__ float sx[4][F];
    int tid = threadIdx.x;
    for (int idx = tid; idx < F * 64; idx += 256) sW[idx >> 6][idx & 63] = W[idx];
    if (tid < 64) sb[tid] = b[tid];
    int base = blockIdx.x * 64;
    int r = tid >> 6, j = tid & 63;
    for (int it = 0; it < 16; ++it) {
        int row0 = base + it * 4;
        __syncthreads();   // covers W-load on first iter, prior compute on later iters
        for (int idx = tid; idx < 4 * F; idx += 256) {
            int rr = idx / F, k = idx - rr * F;
            int row = row0 + rr;
            sx[rr][k] = (row < n) ? x[(size_t)row * F + k] : 0.f;
        }
        __syncthreads();
        int row = row0 + r;
        if (row < n) {
            float acc = sb[j];
#pragma unroll
            for (int k = 0; k < F; ++k) acc += sx[r][k] * sW[k][j];
            out[(size_t)row * 64 + j] = f2b(acc);
        }
    }
}

// cnt[dst[e]] += 1
__global__ void count_kernel(const int* __restrict__ dst, float* __restrict__ cnt, int ne) {
    int e = blockIdx.x * 256 + threadIdx.x;
    if (e < ne) atomicAddF(&cnt[dst[e]], 1.0f);
}

// agg[dst[e], :] += h[src[e], :]   (one wave per edge, lane = feature)
__global__ void agg_kernel(const bf16* __restrict__ h, const int* __restrict__ src,
                           const int* __restrict__ dst, float* __restrict__ agg, int ne) {
    int e = blockIdx.x * 4 + (threadIdx.x >> 6);
    if (e >= ne) return;
    int lane = threadIdx.x & 63;
    int s = src[e], d = dst[e];
    float v = b2f(h[(size_t)s * 64 + lane]);
    atomicAddF(&agg[(size_t)d * 64 + lane], v);
}

// out[i,j] = relu( (agg[i,:]/max(cnt_i,1)) . Wl[:,j] + bl[j] + xd[i,:] . Wr[:,j] )
// xd is bf16; writes bf16 (outb) and/or f32 (outf). In-place outb==xd is safe
// (each block reads a 4-row tile into LDS, syncs, then writes the same rows) —
// but ONLY once no other kernel still needs xd.
// HEAD=true additionally computes logits = relu(t2 @ Wh1 + bh1) @ Wh2 + bh2
// directly from the just-computed row (staged in LDS, wave-local), avoiding a
// separate head kernel and the 256 MB re-read of t2.
template<bool HEAD>
__global__ void sage_out_kernel(const float* __restrict__ agg, const float* __restrict__ cnt,
                                const bf16* __restrict__ xd,
                                const float* __restrict__ Wl, const float* __restrict__ bl,
                                const float* __restrict__ Wr,
                                float* __restrict__ outf, bf16* __restrict__ outb,
                                const float* __restrict__ Wh1, const float* __restrict__ bh1,
                                const float* __restrict__ Wh2, const float* __restrict__ bh2,
                                float* __restrict__ logits, int n) {
    __shared__ float sWl[64][64];
    __shared__ float sWr[64][64];
    __shared__ float sW1[HEAD ? 64 : 1][64];
    __shared__ float sbl[64];
    __shared__ float sb1[HEAD ? 64 : 1];
    __shared__ float sW2[HEAD ? 128 : 2];
    __shared__ float sb2[2];
    __shared__ float sm[4][64];
    __shared__ float sx[4][64];
    __shared__ float sc[4];
    int tid = threadIdx.x;
    for (int idx = tid; idx < 4096; idx += 256) {
        sWl[idx >> 6][idx & 63] = Wl[idx];
        sWr[idx >> 6][idx & 63] = Wr[idx];
        if (HEAD) sW1[idx >> 6][idx & 63] = Wh1[idx];
    }
    if (tid < 64) sbl[tid] = bl[tid];
    if (HEAD) {
        if (tid >= 64 && tid < 128) sb1[tid - 64] = bh1[tid - 64];
        if (tid >= 128 && tid < 256) sW2[tid - 128] = Wh2[tid - 128];
        if (tid < 2) sb2[tid] = bh2[tid];
    }
    int base = blockIdx.x * 64;
    int r = tid >> 6, j = tid & 63;
    for (int it = 0; it < 16; ++it) {
        int row0 = base + it * 4;
        __syncthreads();
        {
            int rr = tid >> 6, k = tid & 63;
            int row = row0 + rr;
            sm[rr][k] = (row < n) ? agg[(size_t)row * 64 + k] : 0.f;
            sx[rr][k] = (row < n) ? b2f(xd[(size_t)row * 64 + k]) : 0.f;
        }
        if (tid < 4) sc[tid] = (row0 + tid < n) ? cnt[row0 + tid] : 1.f;
        __syncthreads();
        int row = row0 + r;
        if (row < n) {
            float inv = 1.f / fmaxf(sc[r], 1.f);
            float accl = 0.f, accr = 0.f;
#pragma unroll
            for (int k = 0; k < 64; ++k) {
                accl += sm[r][k] * sWl[k][j];
                accr += sx[r][k] * sWr[k][j];
            }
            float v = fmaxf(accl * inv + sbl[j] + accr, 0.f);
            if (outf) outf[(size_t)row * 64 + j] = v;
            if (outb) outb[(size_t)row * 64 + j] = f2b(v);
            if (HEAD) {
                // Wave-local t2 staging: each wave owns row r; LDS ops retire in
                // program order per wave, so the write below is ordered after the
                // reads in the k-loop above, and the reads below after the write.
                sm[r][j] = v;
                float acc = sb1[j];
#pragma unroll
                for (int k = 0; k < 64; ++k) acc += sm[r][k] * sW1[k][j];
                float hid = fmaxf(acc, 0.f);
                float p0 = hid * sW2[j * 2 + 0];
                float p1 = hid * sW2[j * 2 + 1];
#pragma unroll
                for (int off = 32; off; off >>= 1) {
                    p0 += __shfl_down(p0, off);
                    p1 += __shfl_down(p1, off);
                }
                if (j == 0) {
                    logits[(size_t)row * 2 + 0] = p0 + sb2[0];
                    logits[(size_t)row * 2 + 1] = p1 + sb2[1];
                }
            }
        }
    }
}

extern "C" void kernel_launch(void* const* d_in, const int* in_sizes, int n_in,
                              void* d_out, int out_size, void* d_ws, size_t ws_size,
                              hipStream_t stream) {
    const float* x_tx   = (const float*)d_in[0];
    const float* x_w    = (const float*)d_in[1];
    const int*   src_tw = (const int*)d_in[2];
    const int*   dst_tw = (const int*)d_in[3];
    const int*   src_wt = (const int*)d_in[4];
    const int*   dst_wt = (const int*)d_in[5];
    const float* Win_tx = (const float*)d_in[6];
    const float* bin_tx = (const float*)d_in[7];
    const float* Win_w  = (const float*)d_in[8];
    const float* bin_w  = (const float*)d_in[9];
    const float* Wl1_tw = (const float*)d_in[10];
    const float* bl1_tw = (const float*)d_in[11];
    const float* Wr1_tw = (const float*)d_in[12];
    const float* Wl1_wt = (const float*)d_in[13];
    const float* bl1_wt = (const float*)d_in[14];
    const float* Wr1_wt = (const float*)d_in[15];
    const float* Wl2_tw = (const float*)d_in[16];
    const float* bl2_tw = (const float*)d_in[17];
    const float* Wr2_tw = (const float*)d_in[18];
    const float* Wl2_wt = (const float*)d_in[19];
    const float* bl2_wt = (const float*)d_in[20];
    const float* Wr2_wt = (const float*)d_in[21];
    const float* Wh1    = (const float*)d_in[22];
    const float* bh1    = (const float*)d_in[23];
    const float* Wh2    = (const float*)d_in[24];
    const float* bh2    = (const float*)d_in[25];

    const int n_tx  = in_sizes[0] / 64;
    const int n_w   = in_sizes[1] / 32;
    const int ne_tw = in_sizes[2];
    const int ne_wt = in_sizes[4];

    // workspace layout (~485 MB) — aggE and aggC are SEPARATE (both alive in conv1)
    float* aggE   = (float*)d_ws;                         // n_tx*64 f32 : agg into tx
    float* aggC   = aggE + (size_t)n_tx * 64;             // n_w *64 f32 : agg into wallets
    bf16*  A      = (bf16*)(aggC + (size_t)n_w * 64);     // n_tx*64 bf16: h_tx -> t1 (in-place)
    bf16*  B      = A + (size_t)n_tx * 64;                // n_w *64 bf16: h_w  -> w1 (in-place)
    float* cnt_w  = (float*)(B + (size_t)n_w * 64);       // n_w
    float* cnt_tx = cnt_w + n_w;                          // n_tx

    float* out_logits = (float*)d_out;
    float* out_t2 = out_logits + (size_t)n_tx * 2;
    float* out_w2 = out_t2 + (size_t)n_tx * 64;

    const size_t bytes_aggw  = (size_t)n_w * 64 * sizeof(float);
    const size_t bytes_aggtx = (size_t)n_tx * 64 * sizeof(float);

    dim3 blk(256);
    int grid_proj_tx = (n_tx + 63) / 64;
    int grid_proj_w  = (n_w + 63) / 64;
    int grid_cnt_tw  = (ne_tw + 255) / 256;
    int grid_cnt_wt  = (ne_wt + 255) / 256;
    int grid_agg_tw  = (ne_tw + 3) / 4;
    int grid_agg_wt  = (ne_wt + 3) / 4;

    // zero counters + agg buffers, project inputs, degree counts
    hipMemsetAsync(cnt_w, 0, (size_t)n_w * sizeof(float), stream);
    hipMemsetAsync(cnt_tx, 0, (size_t)n_tx * sizeof(float), stream);
    hipMemsetAsync(aggE, 0, bytes_aggtx, stream);
    hipMemsetAsync(aggC, 0, bytes_aggw, stream);
    proj_kernel<64><<<grid_proj_tx, blk, 0, stream>>>(x_tx, Win_tx, bin_tx, A, n_tx);
    proj_kernel<32><<<grid_proj_w, blk, 0, stream>>>(x_w, Win_w, bin_w, B, n_w);
    count_kernel<<<grid_cnt_tw, blk, 0, stream>>>(dst_tw, cnt_w, ne_tw);
    count_kernel<<<grid_cnt_wt, blk, 0, stream>>>(dst_wt, cnt_tx, ne_wt);

    // conv1: BOTH aggregations first (from layer-0 features), THEN both epilogues
    agg_kernel<<<grid_agg_tw, blk, 0, stream>>>(A, src_tw, dst_tw, aggC, ne_tw);  // h_tx -> w
    agg_kernel<<<grid_agg_wt, blk, 0, stream>>>(B, src_wt, dst_wt, aggE, ne_wt);  // h_w  -> tx
    sage_out_kernel<false><<<grid_proj_w, blk, 0, stream>>>(
        aggC, cnt_w, B, Wl1_tw, bl1_tw, Wr1_tw,
        nullptr, B, nullptr, nullptr, nullptr, nullptr, nullptr, n_w);            // w1 (in-place B)
    sage_out_kernel<false><<<grid_proj_tx, blk, 0, stream>>>(
        aggE, cnt_tx, A, Wl1_wt, bl1_wt, Wr1_wt,
        nullptr, A, nullptr, nullptr, nullptr, nullptr, nullptr, n_tx);           // t1 (in-place A)

    // conv2: re-zero agg buffers, both aggregations (from t1=A, w1=B), both epilogues
    hipMemsetAsync(aggC, 0, bytes_aggw, stream);
    hipMemsetAsync(aggE, 0, bytes_aggtx, stream);
    agg_kernel<<<grid_agg_tw, blk, 0, stream>>>(A, src_tw, dst_tw, aggC, ne_tw);  // t1 -> w
    agg_kernel<<<grid_agg_wt, blk, 0, stream>>>(B, src_wt, dst_wt, aggE, ne_wt);  // w1 -> tx
    sage_out_kernel<false><<<grid_proj_w, blk, 0, stream>>>(
        aggC, cnt_w, B, Wl2_tw, bl2_tw, Wr2_tw,
        out_w2, nullptr, nullptr, nullptr, nullptr, nullptr, nullptr, n_w);       // w2 -> f32 out
    // t2 epilogue + fused head: writes out_t2 AND out_logits in one pass
    sage_out_kernel<true><<<grid_proj_tx, blk, 0, stream>>>(
        aggE, cnt_tx, A, Wl2_wt, bl2_wt, Wr2_wt,
        out_t2, nullptr, Wh1, bh1, Wh2, bh2, out_logits, n_tx);                   // t2 + logits
}